// Round 1
// baseline (39.006 us; speedup 1.0000x reference)
//
#include <hip/hip_runtime.h>
#include <hip/hip_bf16.h>

#define S 1024
#define NSPLIT 8
#define BLK 256

// Kernel 1: per-(batch, split) partial pairwise hinge sums.
// Block (b, split) handles all j in {split+1, split+1+NSPLIT, ...} < S,
// inner loop over i < j parallel across threads. LDS-staged masked p/l.
__global__ __launch_bounds__(BLK) void rank_partial_kernel(
    const float* __restrict__ preds,
    const float* __restrict__ labels,
    float* __restrict__ partial) {
  const int b = blockIdx.x / NSPLIT;
  const int split = blockIdx.x % NSPLIT;

  __shared__ float2 pl[S];   // (p_masked, l_masked)
  __shared__ float  msk[S];  // 1.0 if label != -1 else 0.0

  const float* pr = preds + (size_t)b * S;
  const float* lr = labels + (size_t)b * S;
  for (int i = threadIdx.x; i < S; i += BLK) {
    float lab = lr[i];
    float m = (lab != -1.0f) ? 1.0f : 0.0f;
    pl[i] = make_float2(pr[i] * m, lab * m);
    msk[i] = m;
  }
  __syncthreads();

  float acc = 0.0f;
  for (int j = split + 1; j < S; j += NSPLIT) {
    if (msk[j] == 0.0f) continue;       // uniform across block: cheap skip
    const float pj = pl[j].x;
    const float lj = pl[j].y;
    for (int i = threadIdx.x; i < j; i += BLK) {
      float2 v = pl[i];
      float dp = v.x - pj;              // p_i - p_j
      float dl = v.y - lj;              // l_i - l_j
      float s = (dl > 0.0f) ? 1.0f : ((dl < 0.0f) ? -1.0f : 0.0f);
      float t = fmaf(-s, dp, 1.0f);     // 1 - sign*dp
      acc += fmaxf(t, 0.0f);
    }
  }

  // Deterministic block reduction: wave shuffle tree, then LDS across waves.
  for (int off = 32; off > 0; off >>= 1)
    acc += __shfl_down(acc, off, 64);

  __shared__ float wsum[BLK / 64];
  const int wid = threadIdx.x >> 6;
  const int lane = threadIdx.x & 63;
  if (lane == 0) wsum[wid] = acc;
  __syncthreads();
  if (threadIdx.x == 0) {
    float tot = 0.0f;
    for (int w = 0; w < BLK / 64; ++w) tot += wsum[w];
    partial[blockIdx.x] = tot;
  }
}

// Kernel 2: one wave. Lane b combines the NSPLIT partials of batch b,
// normalizes by len^2, reduces across batches, writes the 2 outputs.
__global__ __launch_bounds__(64) void rank_final_kernel(
    const float* __restrict__ partial,
    const int* __restrict__ lens,
    float* __restrict__ out,
    int B) {
  const int b = threadIdx.x;  // B == 64 == one wave
  float norm = 0.0f;
  float sents = 0.0f;
  if (b < B) {
    float sum = 0.0f;
    for (int s = 0; s < NSPLIT; ++s) sum += partial[b * NSPLIT + s];
    float len = (float)lens[b];
    norm = sum / (len * len);
    sents = (lens[b] != 0) ? 1.0f : 0.0f;
  }
  for (int off = 32; off > 0; off >>= 1) {
    norm += __shfl_down(norm, off, 64);
    sents += __shfl_down(sents, off, 64);
  }
  if (threadIdx.x == 0) {
    out[0] = norm / sents;
    out[1] = sents;
  }
}

extern "C" void kernel_launch(void* const* d_in, const int* in_sizes, int n_in,
                              void* d_out, int out_size, void* d_ws, size_t ws_size,
                              hipStream_t stream) {
  const float* preds  = (const float*)d_in[0];
  const float* labels = (const float*)d_in[1];
  const int*   lens   = (const int*)d_in[2];
  float* out = (float*)d_out;

  const int B = in_sizes[2];             // 64
  float* partial = (float*)d_ws;         // B * NSPLIT floats

  rank_partial_kernel<<<dim3(B * NSPLIT), dim3(BLK), 0, stream>>>(preds, labels, partial);
  rank_final_kernel<<<dim3(1), dim3(64), 0, stream>>>(partial, lens, out, B);
}

// Round 2
// 25.882 us; speedup vs baseline: 1.5071x; 1.5071x over previous
//
#include <hip/hip_runtime.h>
#include <hip/hip_bf16.h>

#define S 1024
#define NB 8      // blocks per batch
#define BLK 256   // 4 waves per block; 32 waves per batch = 16 j-tiles x 2 i-halves

// Kernel 1: pairwise hinge partial sums.
// Per batch: 16 j-tiles of 64 (one wave-lane per j, p_j/l_j/mask_j in regs),
// i-loop broadcasts pl[i] from LDS (wave-uniform address). Each tile's i-range
// is split across 2 waves; the intra-tile triangle is predicated in half 1.
__global__ __launch_bounds__(BLK) void rank_partial_kernel(
    const float* __restrict__ preds,
    const float* __restrict__ labels,
    float* __restrict__ partial) {
  const int b  = blockIdx.x / NB;
  const int nb = blockIdx.x % NB;

  __shared__ float2 pl[S];  // (p*mask, l*mask)

  const float* pr = preds + (size_t)b * S;
  const float* lr = labels + (size_t)b * S;
  for (int i = threadIdx.x; i < S; i += BLK) {
    float lab = lr[i];
    float m = (lab != -1.0f) ? 1.0f : 0.0f;
    pl[i] = make_float2(pr[i] * m, lab * m);
  }
  __syncthreads();

  const int wv   = threadIdx.x >> 6;   // 0..3
  const int lane = threadIdx.x & 63;
  const int gw   = nb * 4 + wv;        // 0..31 within batch
  const int tile = gw & 15;            // j-tile index 0..15
  const int half = gw >> 4;            // i-range half 0..1
  const int j    = tile * 64 + lane;

  const float2 plj = pl[j];
  const float pj = plj.x;
  const float lj = plj.y;
  const float mj = (lr[j] != -1.0f) ? 1.0f : 0.0f;

  const int tbase = tile * 64;
  const int ilo = half ? (tbase >> 1) : 0;
  const int ihi = half ? tbase : (tbase >> 1);

  float acc = 0.0f;
#pragma unroll 4
  for (int i = ilo; i < ihi; ++i) {
    float2 v = pl[i];                  // wave-uniform addr -> LDS broadcast
    float dp = v.x - pj;
    float dl = v.y - lj;
    float s = (float)(dl > 0.0f) - (float)(dl < 0.0f);
    acc += fmaxf(fmaf(-s, dp, 1.0f), 0.0f);
  }
  if (half) {                          // intra-tile triangle, predicated i<j
#pragma unroll 4
    for (int i = tbase; i < tbase + 64; ++i) {
      float2 v = pl[i];
      float dp = v.x - pj;
      float dl = v.y - lj;
      float s = (float)(dl > 0.0f) - (float)(dl < 0.0f);
      float t = fmaxf(fmaf(-s, dp, 1.0f), 0.0f);
      acc += (i < j) ? t : 0.0f;
    }
  }
  acc *= mj;

  // Deterministic block reduction.
  for (int off = 32; off > 0; off >>= 1)
    acc += __shfl_down(acc, off, 64);
  __shared__ float wsum[BLK / 64];
  if (lane == 0) wsum[wv] = acc;
  __syncthreads();
  if (threadIdx.x == 0)
    partial[blockIdx.x] = wsum[0] + wsum[1] + wsum[2] + wsum[3];
}

// Kernel 2: one wave. Lane b combines the NB partials of batch b,
// normalizes by len^2, reduces across batches, writes the 2 outputs.
__global__ __launch_bounds__(64) void rank_final_kernel(
    const float* __restrict__ partial,
    const int* __restrict__ lens,
    float* __restrict__ out,
    int B) {
  const int b = threadIdx.x;  // B == 64 == one wave
  float norm = 0.0f;
  float sents = 0.0f;
  if (b < B) {
    float sum = 0.0f;
    for (int s = 0; s < NB; ++s) sum += partial[b * NB + s];
    float len = (float)lens[b];
    norm = sum / (len * len);
    sents = (lens[b] != 0) ? 1.0f : 0.0f;
  }
  for (int off = 32; off > 0; off >>= 1) {
    norm += __shfl_down(norm, off, 64);
    sents += __shfl_down(sents, off, 64);
  }
  if (threadIdx.x == 0) {
    out[0] = norm / sents;
    out[1] = sents;
  }
}

extern "C" void kernel_launch(void* const* d_in, const int* in_sizes, int n_in,
                              void* d_out, int out_size, void* d_ws, size_t ws_size,
                              hipStream_t stream) {
  const float* preds  = (const float*)d_in[0];
  const float* labels = (const float*)d_in[1];
  const int*   lens   = (const int*)d_in[2];
  float* out = (float*)d_out;

  const int B = in_sizes[2];             // 64
  float* partial = (float*)d_ws;         // B * NB floats

  rank_partial_kernel<<<dim3(B * NB), dim3(BLK), 0, stream>>>(preds, labels, partial);
  rank_final_kernel<<<dim3(1), dim3(64), 0, stream>>>(partial, lens, out, B);
}

// Round 3
// 16.179 us; speedup vs baseline: 2.4109x; 1.5997x over previous
//
#include <hip/hip_runtime.h>
#include <hip/hip_bf16.h>

#define S 1024
#define NBB 8     // blocks per batch
#define BLK 256   // 4 waves

// Per-pair hinge: relu(1 - sign(l_i - l_j) * (p_i - p_j))
// sign*dp via sign-bit xor; dl==0 tie forces hinge = 1.
__device__ __forceinline__ float pair_term(float2 v, float pj, float lj) {
  float dp = v.x - pj;
  float dl = v.y - lj;
  unsigned sx = __float_as_uint(dl) & 0x80000000u;
  float x = __uint_as_float(__float_as_uint(dp) ^ sx);   // sign(dl)*dp (dl!=0)
  float h = fmaxf(1.0f - x, 0.0f);
  return (dl == 0.0f) ? 1.0f : h;
}

// Kernel 1: block nb of batch b owns j-tile pair (t=nb, u=15-nb).
// Wave w handles i in [w*16t,(w+1)*16t) for tile t, [w*16u,(w+1)*16u) for u,
// plus half a triangle: waves 0,2 -> triangle t halves; 1,3 -> triangle u.
// Every wave does exactly 272 i-iterations -> perfect balance.
__global__ __launch_bounds__(BLK) void rank_partial_kernel(
    const float* __restrict__ preds,
    const float* __restrict__ labels,
    float* __restrict__ partial) {
  const int b  = blockIdx.x / NBB;
  const int nb = blockIdx.x % NBB;

  __shared__ float2 pl[S];   // (p*mask, l*mask)
  __shared__ float  msk[S];

  const float* pr = preds + (size_t)b * S;
  const float* lr = labels + (size_t)b * S;
  {
    const float4 pv = ((const float4*)pr)[threadIdx.x];
    const float4 lv = ((const float4*)lr)[threadIdx.x];
    const float lm[4] = {lv.x, lv.y, lv.z, lv.w};
    const float pm[4] = {pv.x, pv.y, pv.z, pv.w};
#pragma unroll
    for (int e = 0; e < 4; ++e) {
      float m = (lm[e] != -1.0f) ? 1.0f : 0.0f;
      pl[threadIdx.x * 4 + e] = make_float2(pm[e] * m, lm[e] * m);
      msk[threadIdx.x * 4 + e] = m;
    }
  }
  __syncthreads();

  const int wv   = threadIdx.x >> 6;
  const int lane = threadIdx.x & 63;
  const int t = nb;         // j-tile 1
  const int u = 15 - nb;    // j-tile 2
  const int jt = t * 64 + lane;
  const int ju = u * 64 + lane;

  const float2 pjt = pl[jt];
  const float2 pju = pl[ju];
  const float  mjt = msk[jt];
  const float  mju = msk[ju];

  const float4* pl4 = (const float4*)pl;

  float acc_t = 0.0f, acc_u = 0.0f;

  // Uniform i-ranges (wave-quarter of [0, 64*t) and [0, 64*u)), 2 i per b128.
  {
    const int lo = wv * 16 * t, hi = lo + 16 * t;
#pragma unroll 4
    for (int i = lo; i < hi; i += 2) {
      float4 q = pl4[i >> 1];
      acc_t += pair_term(make_float2(q.x, q.y), pjt.x, pjt.y);
      acc_t += pair_term(make_float2(q.z, q.w), pjt.x, pjt.y);
    }
  }
  {
    const int lo = wv * 16 * u, hi = lo + 16 * u;
#pragma unroll 4
    for (int i = lo; i < hi; i += 2) {
      float4 q = pl4[i >> 1];
      acc_u += pair_term(make_float2(q.x, q.y), pju.x, pju.y);
      acc_u += pair_term(make_float2(q.z, q.w), pju.x, pju.y);
    }
  }
  // Triangle halves (predicated i < j).
  {
    const bool ut = (wv & 1);                 // waves 1,3 -> tile u
    const int tb = (ut ? u : t) * 64 + (wv >> 1) * 32;
    const int j  = ut ? ju : jt;
    const float pj = ut ? pju.x : pjt.x;
    const float lj = ut ? pju.y : pjt.y;
    float a = 0.0f;
#pragma unroll 4
    for (int i = tb; i < tb + 32; i += 2) {
      float4 q = pl4[i >> 1];
      a += (i     < j) ? pair_term(make_float2(q.x, q.y), pj, lj) : 0.0f;
      a += (i + 1 < j) ? pair_term(make_float2(q.z, q.w), pj, lj) : 0.0f;
    }
    if (ut) acc_u += a; else acc_t += a;
  }

  float acc = acc_t * mjt + acc_u * mju;

  // Deterministic block reduction.
  for (int off = 32; off > 0; off >>= 1)
    acc += __shfl_down(acc, off, 64);
  __shared__ float wsum[BLK / 64];
  if (lane == 0) wsum[wv] = acc;
  __syncthreads();
  if (threadIdx.x == 0)
    partial[blockIdx.x] = wsum[0] + wsum[1] + wsum[2] + wsum[3];
}

// Kernel 2: one wave finalizes.
__global__ __launch_bounds__(64) void rank_final_kernel(
    const float* __restrict__ partial,
    const int* __restrict__ lens,
    float* __restrict__ out,
    int B) {
  const int b = threadIdx.x;
  float norm = 0.0f, sents = 0.0f;
  if (b < B) {
    float sum = 0.0f;
    for (int s = 0; s < NBB; ++s) sum += partial[b * NBB + s];
    float len = (float)lens[b];
    norm = sum / (len * len);
    sents = (lens[b] != 0) ? 1.0f : 0.0f;
  }
  for (int off = 32; off > 0; off >>= 1) {
    norm += __shfl_down(norm, off, 64);
    sents += __shfl_down(sents, off, 64);
  }
  if (threadIdx.x == 0) {
    out[0] = norm / sents;
    out[1] = sents;
  }
}

extern "C" void kernel_launch(void* const* d_in, const int* in_sizes, int n_in,
                              void* d_out, int out_size, void* d_ws, size_t ws_size,
                              hipStream_t stream) {
  const float* preds  = (const float*)d_in[0];
  const float* labels = (const float*)d_in[1];
  const int*   lens   = (const int*)d_in[2];
  float* out = (float*)d_out;

  const int B = in_sizes[2];             // 64
  float* partial = (float*)d_ws;         // B * NBB floats

  rank_partial_kernel<<<dim3(B * NBB), dim3(BLK), 0, stream>>>(preds, labels, partial);
  rank_final_kernel<<<dim3(1), dim3(64), 0, stream>>>(partial, lens, out, B);
}